// Round 6
// baseline (326.525 us; speedup 1.0000x reference)
//
#include <hip/hip_runtime.h>
#include <hip/hip_bf16.h>

typedef __attribute__((ext_vector_type(8))) short short8v;
typedef __attribute__((ext_vector_type(4))) float f32x4;

constexpr int B_  = 8;
constexpr int NH  = 12;
constexpr int DIM = 768;
constexpr int HD  = 64;
constexpr int N_  = 1025;
constexpr int NSP = 1024;
constexpr int K3  = 2304;
constexpr int KROWS = 1056;  // padded K rows (zeros past 1024)
constexpr int NPAD  = 1056;  // ct table length
constexpr int VT    = 33;    // kv tiles; V stored [bh][VT][64][32]

// ---- workspace byte offsets ----
constexpr size_t OFF_MASK  = 0;                                   // 8448 f32
constexpr size_t OFF_PC    = 49152;                                // 8 f32
constexpr size_t OFF_QKVWT = 65536;                               // [2304][768] bf16
constexpr size_t OFF_PROJWT= OFF_QKVWT + (size_t)K3*768*2;
constexpr size_t OFF_Q     = OFF_PROJWT + (size_t)768*768*2;      // [bh][1025][64]
constexpr size_t OFF_K     = OFF_Q + (size_t)B_*NH*N_*HD*2;       // [bh][1056][64]
constexpr size_t K_BYTES   = (size_t)B_*NH*KROWS*HD*2;
constexpr size_t OFF_V     = OFF_K + K_BYTES;                     // [bh][33][64][32]
constexpr size_t V_BYTES   = (size_t)B_*NH*VT*64*32*2;
constexpr size_t OFF_AO    = OFF_V + V_BYTES;                     // [8192][768] bf16
constexpr size_t OFF_PS    = OFF_AO + (size_t)8192*768*2;         // [64][768] f32
constexpr size_t OFF_PM    = OFF_PS + 64*768*4;                   // [64][768] f32

__device__ inline float b2f(unsigned short u) {
  union { unsigned int ui; float f; } x; x.ui = ((unsigned int)u) << 16; return x.f;
}
__device__ inline unsigned short f2b(float f) {
  union { float f; unsigned int u; } x; x.f = f;
  unsigned int r = x.u + 0x7FFFu + ((x.u >> 16) & 1u);
  return (unsigned short)(r >> 16);
}
__device__ inline unsigned int cvtpk(float lo, float hi) {
  unsigned int r;
  asm("v_cvt_pk_bf16_f32 %0, %1, %2" : "=v"(r) : "v"(lo), "v"(hi));
  return r;
}
__device__ inline short8v pack8(float4 lo, float4 hi) {
  union { unsigned int u[4]; short8v s; } r;
  r.u[0] = cvtpk(lo.x, lo.y); r.u[1] = cvtpk(lo.z, lo.w);
  r.u[2] = cvtpk(hi.x, hi.y); r.u[3] = cvtpk(hi.z, hi.w);
  return r.s;
}
__device__ inline float fexp2(float x) {
  float r;
  asm("v_exp_f32 %0, %1" : "=v"(r) : "v"(x));
  return r;
}

// ---------------- prep: pad K/V + mask convert + per-b count ----------------
__global__ __launch_bounds__(256) void prep(
    const unsigned char* __restrict__ mraw, float* __restrict__ mask_f,
    float* __restrict__ pcnt, unsigned short* __restrict__ kW,
    unsigned short* __restrict__ vW)
{
  const int g = blockIdx.x, t = threadIdx.x;
  if (g < 96) {
    unsigned short* kbase = kW + (size_t)g * KROWS * HD + 1025 * HD;
    for (int i = t; i < 31 * 64; i += 256) kbase[i] = 0;
    unsigned short* vbase = vW + ((size_t)g * VT + 32) * 2048;
    for (int i = t; i < 64 * 31; i += 256) {
      const int d = i / 31, c = i - d * 31;
      vbase[d * 32 + 1 + c] = 0;
    }
    return;
  }
  __shared__ int flags[2];
  __shared__ float cnt8[8];
  if (t < 2) flags[t] = 0;
  if (t < 8) cnt8[t] = 0.f;
  __syncthreads();
  const int n = B_ * N_;
  int f1 = 0, f0 = 0;
  for (int i = t; i < n; i += 256) {
    unsigned char vv = mraw[i];
    if (vv) { int m = i & 3; if (m == 1) f1 = 1; if (m == 0) f0 = 1; }
  }
  if (f1) atomicOr(&flags[0], 1);
  if (f0) atomicOr(&flags[1], 1);
  __syncthreads();
  const bool isBool = flags[0] != 0;
  const bool isInt  = !isBool && (flags[1] != 0);
  for (int i = t; i < n; i += 256) {
    float v;
    if (isBool)     v = mraw[i] ? 1.f : 0.f;
    else if (isInt) v = ((const int*)mraw)[i] ? 1.f : 0.f;
    else            v = ((const float*)mraw)[i];
    mask_f[i] = v;
    const int b = i / 1025, nn = i - b * 1025;
    if (nn > 0) atomicAdd(&cnt8[b], v);
  }
  __syncthreads();
  if (t < 8) pcnt[t] = cnt8[t];
}

// ---------------- combined weight transpose f32[K][N] -> bf16[N][768] ------
__global__ void transpose_cvt2(const float* __restrict__ qkv_w,
                               const float* __restrict__ proj_w,
                               unsigned short* __restrict__ qkvwT,
                               unsigned short* __restrict__ projwT)
{
  __shared__ float tile[32][33];
  const int bx = blockIdx.x, by = blockIdx.y;
  const float* in; unsigned short* out; int N, n0;
  if (bx < 72) { in = qkv_w;  out = qkvwT;  N = K3;  n0 = bx * 32; }
  else         { in = proj_w; out = projwT; N = 768; n0 = (bx - 72) * 32; }
  const int tx = threadIdx.x, ty = threadIdx.y;
  tile[ty][tx] = in[(size_t)(by * 32 + ty) * N + n0 + tx];
  __syncthreads();
  out[(size_t)(n0 + ty) * 768 + by * 32 + tx] = f2b(tile[tx][ty]);
}

// ---------------- bf16 MFMA GEMM ----------------
// MODE 0: A = x (f32, converted in staging), epilogue scatters q/k/v
// MODE 1: A = attn_out (bf16), epilogue = fused masked-avg/max pooling
template<int MODE>
__global__ __launch_bounds__(256) void gemm_bf16(
    const void* __restrict__ Araw, const unsigned short* __restrict__ BT,
    const float* __restrict__ bias,
    unsigned short* __restrict__ qo, unsigned short* __restrict__ ko,
    unsigned short* __restrict__ vo,
    const float* __restrict__ mask_f, float* __restrict__ psum,
    float* __restrict__ pmax, int M)
{
  constexpr int LDK = 768;
  __shared__ unsigned short As[128 * 40];
  __shared__ unsigned short Bs[128 * 40];
  __shared__ float Ms[128];
  const int t = threadIdx.x;
  const int l = t & 63, w = t >> 6;
  const int lg16 = l >> 4, lm16 = l & 15;
  const int wr = w >> 1, wc = w & 1;
  const int m0 = blockIdx.y * 128, n0 = blockIdx.x * 128;

  if (MODE == 1 && t < 128) {
    const int b0 = m0 >> 10, nr = m0 & 1023;
    Ms[t] = mask_f[b0 * N_ + 1 + nr + t];
  }

  f32x4 acc[4][4];
#pragma unroll
  for (int i = 0; i < 4; ++i)
#pragma unroll
    for (int j = 0; j < 4; ++j) acc[i][j] = (f32x4){0.f, 0.f, 0.f, 0.f};

  const int srow = t >> 1, soff = (t & 1) * 16;
  const bool avalid = (MODE == 0) ? (m0 + srow < M) : true;
  const float* Af = (const float*)Araw;
  const unsigned short* Ab = (const unsigned short*)Araw;
  const float* Aptr_f = Af + (size_t)(m0 + srow) * LDK + soff;
  const unsigned short* Aptr_b = Ab + (size_t)(m0 + srow) * LDK + soff;
  const unsigned short* Bptr = BT + (size_t)(n0 + srow) * LDK + soff;
  const short8v z8 = {0, 0, 0, 0, 0, 0, 0, 0};

  for (int k0 = 0; k0 < LDK; k0 += 32) {
    short8v a0 = z8, a1 = z8;
    if (MODE == 0) {
      if (avalid) {
        float4 f0 = *(const float4*)(Aptr_f + k0);
        float4 f1 = *(const float4*)(Aptr_f + k0 + 4);
        float4 f2 = *(const float4*)(Aptr_f + k0 + 8);
        float4 f3 = *(const float4*)(Aptr_f + k0 + 12);
        a0 = pack8(f0, f1);
        a1 = pack8(f2, f3);
      }
    } else {
      a0 = *(const short8v*)(Aptr_b + k0);
      a1 = *(const short8v*)(Aptr_b + k0 + 8);
    }
    short8v b0 = *(const short8v*)(Bptr + k0);
    short8v b1 = *(const short8v*)(Bptr + k0 + 8);
    __syncthreads();
    *(short8v*)&As[srow * 40 + soff]     = a0;
    *(short8v*)&As[srow * 40 + soff + 8] = a1;
    *(short8v*)&Bs[srow * 40 + soff]     = b0;
    *(short8v*)&Bs[srow * 40 + soff + 8] = b1;
    __syncthreads();
    short8v af[4], bf[4];
#pragma unroll
    for (int mi = 0; mi < 4; ++mi)
      af[mi] = *(short8v*)&As[(wr * 64 + mi * 16 + lm16) * 40 + lg16 * 8];
#pragma unroll
    for (int ni = 0; ni < 4; ++ni)
      bf[ni] = *(short8v*)&Bs[(wc * 64 + ni * 16 + lm16) * 40 + lg16 * 8];
#pragma unroll
    for (int mi = 0; mi < 4; ++mi)
#pragma unroll
      for (int ni = 0; ni < 4; ++ni)
        acc[mi][ni] = __builtin_amdgcn_mfma_f32_16x16x32_bf16(
            af[mi], bf[ni], acc[mi][ni], 0, 0, 0);
  }

  if (MODE == 1) {
    // ---- fused pooling epilogue: no po write at all ----
    __syncthreads();
    float* sred = (float*)As;        // [2][128]
    float* xred = sred + 256;        // [2][128]
#pragma unroll
    for (int ni = 0; ni < 4; ++ni) {
      const int cidx = wc * 64 + ni * 16 + lm16;
      const float bv = bias[n0 + cidx];
      float s = 0.f, xm = -3.402823466e+38f;
#pragma unroll
      for (int mi = 0; mi < 4; ++mi)
#pragma unroll
        for (int r = 0; r < 4; ++r) {
          const float v = acc[mi][ni][r] + bv;
          const float m = Ms[wr * 64 + mi * 16 + lg16 * 4 + r];
          s = fmaf(v, m, s);
          xm = fmaxf(xm, v);
        }
      s += __shfl_xor(s, 16);
      s += __shfl_xor(s, 32);
      xm = fmaxf(xm, __shfl_xor(xm, 16));
      xm = fmaxf(xm, __shfl_xor(xm, 32));
      if (lg16 == 0) {
        sred[wr * 128 + cidx] = s;
        xred[wr * 128 + cidx] = xm;
      }
    }
    __syncthreads();
    if (t < 128) {
      const float s  = sred[t] + sred[128 + t];
      const float xm = fmaxf(xred[t], xred[128 + t]);
      psum[(size_t)blockIdx.y * 768 + n0 + t] = s;
      pmax[(size_t)blockIdx.y * 768 + n0 + t] = xm;
    }
  } else {
#pragma unroll
    for (int mi = 0; mi < 4; ++mi) {
      const int row0 = m0 + wr * 64 + mi * 16 + lg16 * 4;
#pragma unroll
      for (int ni = 0; ni < 4; ++ni) {
        const int col = n0 + wc * 64 + ni * 16 + lm16;
        const int which = col / 768;
        const int rem = col - which * 768;
        const int head = rem >> 6, d = rem & 63;
        const float bv = bias[col];
#pragma unroll
        for (int r = 0; r < 4; ++r) {
          const int grow = row0 + r;
          if (grow >= M) continue;
          const int b = grow / 1025;
          const int n = grow - b * 1025;
          const unsigned short val = f2b(acc[mi][ni][r] + bv);
          const int bh = b * NH + head;
          if (which == 0)
            qo[((size_t)bh * N_ + n) * HD + d] = val;
          else if (which == 1)
            ko[((size_t)bh * KROWS + n) * HD + d] = val;
          else
            vo[((size_t)bh * VT + (n >> 5)) * 2048 + d * 32 + (n & 31)] = val;
        }
      }
    }
  }
}

// ---------------- MFMA flash attention v5 ----------------
// 4 waves/block, wave owns 16 q rows. K/V direct from global (L2 via XCD
// swizzle), strength-reduced addressing (imm13 offsets + 1 ptr-add/tile),
// l maintained via ones-column MFMA, raw v_exp softmax, defer-max.
__global__ __launch_bounds__(256) void attn_mfma(
    const unsigned short* __restrict__ qp, const unsigned short* __restrict__ kp,
    const unsigned short* __restrict__ vp, const float* __restrict__ mask_f,
    const float* __restrict__ rph, const float* __restrict__ rpw,
    unsigned short* __restrict__ ao)
{
  const int bid = blockIdx.x;
  const int work = (bid & 7) * 192 + (bid >> 3);
  const int qt = work & 15;
  const int bh = work >> 4;
  const int b = bh / NH, head = bh - b * NH;

  const int t = threadIdx.x, l = t & 63, w = t >> 6;
  const int lg16 = l >> 4, lm16 = l & 15;
  const int w16 = w * 16;
  constexpr float L2E = 1.44269504f;
  constexpr float SCL = 0.125f * L2E;
  constexpr float MCOL = -1.44269504e9f;
  constexpr float THR_L = 5.77f;

  __shared__ float bh_lds[64][33];
  __shared__ float ct_lds[NPAD];
  __shared__ unsigned int arena[3072];            // bw2 [64][48] f32 | p_lds
  float (*bw2_lds)[48] = (float(*)[48])arena;
  unsigned int (*p_lds)[16 * 20] = (unsigned int(*)[16 * 20])arena;

  const unsigned short* qb = qp + (size_t)bh * N_ * HD;
  const unsigned short* kb = kp + (size_t)bh * KROWS * HD;
  const unsigned short* vb = vp + (size_t)bh * VT * 2048;
  const int q0 = qt * 64 + w16;

  for (int i = t; i < NPAD; i += 256)
    ct_lds[i] = (i < N_) ? (MCOL * (1.f - mask_f[b * N_ + i])) : -2e30f;

  short8v qf[2];
#pragma unroll
  for (int kk = 0; kk < 2; ++kk)
    qf[kk] = *(const short8v*)&qb[(size_t)(1 + q0 + lm16) * HD + kk * 32 + lg16 * 8];

  // ---- rel-pos bias tables via MFMA ----
  {
    const int hq = q0 >> 5, wq0 = q0 & 31;
    const f32x4 z4 = (f32x4){0.f, 0.f, 0.f, 0.f};
    f32x4 sbh[2] = {z4, z4};
    f32x4 sbw[3] = {z4, z4, z4};
#pragma unroll
    for (int nt = 0; nt < 2; ++nt) {
      const float* rp = &rph[(size_t)(hq + 31 - (nt * 16 + lm16)) * HD];
#pragma unroll
      for (int kk = 0; kk < 2; ++kk) {
        float4 lo = *(const float4*)&rp[kk * 32 + lg16 * 8];
        float4 hi = *(const float4*)&rp[kk * 32 + lg16 * 8 + 4];
        sbh[nt] = __builtin_amdgcn_mfma_f32_16x16x32_bf16(
            pack8(lo, hi), qf[kk], sbh[nt], 0, 0, 0);
      }
    }
#pragma unroll
    for (int nt = 0; nt < 3; ++nt) {
      int u = wq0 + nt * 16 + lm16;
      u = u > 62 ? 62 : u;
      const float* rp = &rpw[(size_t)u * HD];
#pragma unroll
      for (int kk = 0; kk < 2; ++kk) {
        float4 lo = *(const float4*)&rp[kk * 32 + lg16 * 8];
        float4 hi = *(const float4*)&rp[kk * 32 + lg16 * 8 + 4];
        sbw[nt] = __builtin_amdgcn_mfma_f32_16x16x32_bf16(
            pack8(lo, hi), qf[kk], sbw[nt], 0, 0, 0);
      }
    }
#pragma unroll
    for (int nt = 0; nt < 2; ++nt)
#pragma unroll
      for (int reg = 0; reg < 4; ++reg)
        bh_lds[w16 + lm16][nt * 16 + lg16 * 4 + reg] = sbh[nt][reg] * L2E;
    if (lg16 == 0) bh_lds[w16 + lm16][32] = 0.f;
#pragma unroll
    for (int nt = 0; nt < 3; ++nt)
#pragma unroll
      for (int reg = 0; reg < 4; ++reg)
        bw2_lds[w16 + lm16][nt * 16 + lg16 * 4 + reg] = sbw[nt][reg] * L2E;
  }
  __syncthreads();

  const float mi_s = mask_f[b * N_ + 1 + q0 + lm16];
  const bool mzero = (mi_s == 0.f);
  float bwv[2][4];
#pragma unroll
  for (int nt = 0; nt < 2; ++nt)
#pragma unroll
    for (int reg = 0; reg < 4; ++reg) {
      const int kw = (lg16 * 4 + reg + 16 * nt + 31) & 31;
      bwv[nt][reg] = bw2_lds[w16 + lm16][31 + lm16 - kw];
    }
  const float bw31v = bw2_lds[w16 + lm16][lm16];
  __syncthreads();   // arena handoff: bw2 reads done before p_lds writes

  float m_lm = -1e30f, bh_prev = 0.f;
  f32x4 oacc[4];
#pragma unroll
  for (int dt = 0; dt < 4; ++dt) oacc[dt] = (f32x4){0.f, 0.f, 0.f, 0.f};
  f32x4 lacc = (f32x4){0.f, 0.f, 0.f, 0.f};
  short8v ones;
#pragma unroll
  for (int j = 0; j < 8; ++j) ones[j] = (short)0x3F80;

  unsigned int* pw = &p_lds[w][lm16 * 20 + lg16 * 2];
  const unsigned int* pr = &p_lds[w][lm16 * 20 + lg16 * 4];

  // strength-reduced pointers: per-lane base + imm offsets, +4096B/tile
  const char* kpre = (const char*)kb + lm16 * 128 + lg16 * 16;
  const char* vcur = (const char*)vb + lm16 * 64 + lg16 * 16;
  short8v kfn[4];
  kfn[0] = *(const short8v*)(kpre + 0);
  kfn[1] = *(const short8v*)(kpre + 64);
  kfn[2] = *(const short8v*)(kpre + 2048);
  kfn[3] = *(const short8v*)(kpre + 2112);

  for (int kt = 0; kt < 33; ++kt) {
    short8v kf[4];
#pragma unroll
    for (int i = 0; i < 4; ++i) kf[i] = kfn[i];
    kpre += 4096;
    kfn[0] = *(const short8v*)(kpre + 0);
    kfn[1] = *(const short8v*)(kpre + 64);
    kfn[2] = *(const short8v*)(kpre + 2048);
    kfn[3] = *(const short8v*)(kpre + 2112);
    short8v vf[4];
    vf[0] = *(const short8v*)(vcur + 0);
    vf[1] = *(const short8v*)(vcur + 1024);
    vf[2] = *(const short8v*)(vcur + 2048);
    vf[3] = *(const short8v*)(vcur + 3072);
    vcur += 4096;

    // ---- S^T = mfma(K, Q): lane holds q=lm16, kv=(lg16*4+reg)+16nt ----
    f32x4 s0 = (f32x4){0.f, 0.f, 0.f, 0.f};
    f32x4 s1 = (f32x4){0.f, 0.f, 0.f, 0.f};
    s0 = __builtin_amdgcn_mfma_f32_16x16x32_bf16(kf[0], qf[0], s0, 0, 0, 0);
    s0 = __builtin_amdgcn_mfma_f32_16x16x32_bf16(kf[1], qf[1], s0, 0, 0, 0);
    s1 = __builtin_amdgcn_mfma_f32_16x16x32_bf16(kf[2], qf[0], s1, 0, 0, 0);
    s1 = __builtin_amdgcn_mfma_f32_16x16x32_bf16(kf[3], qf[1], s1, 0, 0, 0);

    // ---- logits (log2 domain) ----
    const float bh_k = bh_lds[w16 + lm16][kt];
    const float edgebias = (kt == 0) ? 0.f : (bh_prev + bw31v);
    bh_prev = bh_k;
    f32x4 ct0 = *(const f32x4*)&ct_lds[kt * 32 + lg16 * 4];
    f32x4 ct1 = *(const f32x4*)&ct_lds[kt * 32 + 16 + lg16 * 4];
    float lg_[2][4];
#pragma unroll
    for (int reg = 0; reg < 4; ++reg) {
      float bias20 = bh_k + bwv[0][reg];
      if (reg == 0) bias20 = (lg16 == 0) ? edgebias : bias20;
      const float ec0 = mzero ? fminf(ct0[reg], MCOL) : ct0[reg];
      lg_[0][reg] = fmaf(SCL, s0[reg], bias20 + ec0);
      const float bias21 = bh_k + bwv[1][reg];
      const float ec1 = mzero ? fminf(ct1[reg], MCOL) : ct1[reg];
      lg_[1][reg] = fmaf(SCL, s1[reg], bias21 + ec1);
    }
    // ---- online softmax, defer-max ----
    float tm = fmaxf(fmaxf(fmaxf(lg_[0][0], lg_[0][1]), fmaxf(lg_[0][2], lg_[0][3])),
                     fmaxf(fmaxf(lg_[1][0], lg_[1][1]), fmaxf(lg_[1][2], lg_[1][3])));
    tm = fmaxf(tm, __shfl_xor(tm, 16));
    tm = fmaxf(tm, __shfl_xor(tm, 32));
    if (__any(tm > m_lm + THR_L)) {
      const float nm = fmaxf(m_lm, tm);
      const float rf = fexp2(m_lm - nm);
      m_lm = nm;
      float rfr[4];
#pragma unroll
      for (int reg = 0; reg < 4; ++reg) rfr[reg] = __shfl(rf, lg16 * 4 + reg);
#pragma unroll
      for (int dt = 0; dt < 4; ++dt)
#pragma unroll
        for (int reg = 0; reg < 4; ++reg) oacc[dt][reg] *= rfr[reg];
#pragma unroll
      for (int reg = 0; reg < 4; ++reg) lacc[reg] *= rfr[reg];
    }
    float p[2][4];
#pragma unroll
    for (int nt = 0; nt < 2; ++nt)
#pragma unroll
      for (int reg = 0; reg < 4; ++reg)
        p[nt][reg] = fexp2(lg_[nt][reg] - m_lm);
    // ---- P -> bf16 -> per-wave LDS -> PV A-fragment ----
    pw[0] = cvtpk(p[0][0], p[0][1]);
    pw[1] = cvtpk(p[0][2], p[0][3]);
    pw[8] = cvtpk(p[1][0], p[1][1]);
    pw[9] = cvtpk(p[1][2], p[1][3]);
    const short8v pa = *(const short8v*)pr;
#pragma unroll
    for (int dt = 0; dt < 4; ++dt)
      oacc[dt] = __builtin_amdgcn_mfma_f32_16x16x32_bf16(pa, vf[dt], oacc[dt], 0, 0, 0);
    lacc = __builtin_amdgcn_mfma_f32_16x16x32_bf16(pa, ones, lacc, 0, 0, 0);
  }

  // ---- epilogue: l lives in lacc (row = q), identical across cols ----
  float inv[4];
#pragma unroll
  for (int reg = 0; reg < 4; ++reg) inv[reg] = 1.f / lacc[reg];
#pragma unroll
  for (int dt = 0; dt < 4; ++dt)
#pragma unroll
    for (int reg = 0; reg < 4; ++reg) {
      const int nsp = q0 + lg16 * 4 + reg;
      const float val = oacc[dt][reg] * inv[reg];
      ao[((size_t)(b * NSP + nsp)) * DIM + head * HD + dt * 16 + lm16] = f2b(val);
    }
}

// ---------------- final pooling reduce ----------------
__global__ __launch_bounds__(256) void pool_stage2(
    const float* __restrict__ psum, const float* __restrict__ pmax,
    const float* __restrict__ pcnt, float* __restrict__ out)
{
  const int b = blockIdx.y;
  const int c = blockIdx.x * 256 + threadIdx.x;
  float s = 0.f, mx = -3.402823466e+38f;
#pragma unroll
  for (int z = 0; z < 8; ++z) {
    s  += psum[(size_t)(b * 8 + z) * 768 + c];
    mx  = fmaxf(mx, pmax[(size_t)(b * 8 + z) * 768 + c]);
  }
  const float cnt = pcnt[b];
  out[b * 1536 + c]       = s / (cnt + 1e-7f);
  out[b * 1536 + 768 + c] = mx;
}

// ---------------- launch ----------------
extern "C" void kernel_launch(void* const* d_in, const int* in_sizes, int n_in,
                              void* d_out, int out_size, void* d_ws, size_t ws_size,
                              hipStream_t stream) {
  const float* x      = (const float*)d_in[0];
  const unsigned char* mraw = (const unsigned char*)d_in[1];
  const float* qkv_w  = (const float*)d_in[2];
  const float* qkv_b  = (const float*)d_in[3];
  const float* proj_w = (const float*)d_in[4];
  const float* proj_b = (const float*)d_in[5];
  const float* rph    = (const float*)d_in[6];
  const float* rpw    = (const float*)d_in[7];

  char* ws = (char*)d_ws;
  float*          mask_f = (float*)(ws + OFF_MASK);
  float*          pcnt   = (float*)(ws + OFF_PC);
  unsigned short* qkvwT  = (unsigned short*)(ws + OFF_QKVWT);
  unsigned short* projwT = (unsigned short*)(ws + OFF_PROJWT);
  unsigned short* qW     = (unsigned short*)(ws + OFF_Q);
  unsigned short* kW     = (unsigned short*)(ws + OFF_K);
  unsigned short* vW     = (unsigned short*)(ws + OFF_V);
  unsigned short* aoW    = (unsigned short*)(ws + OFF_AO);
  float*          psum   = (float*)(ws + OFF_PS);
  float*          pmax   = (float*)(ws + OFF_PM);

  prep<<<97, 256, 0, stream>>>(mraw, mask_f, pcnt, kW, vW);
  transpose_cvt2<<<dim3(96, 24), dim3(32, 32), 0, stream>>>(
      qkv_w, proj_w, qkvwT, projwT);

  gemm_bf16<0><<<dim3(K3 / 128, 65), 256, 0, stream>>>(
      (const void*)x, qkvwT, qkv_b, qW, kW, vW, nullptr, nullptr, nullptr, 8200);

  attn_mfma<<<1536, 256, 0, stream>>>(qW, kW, vW, mask_f, rph, rpw, aoW);

  gemm_bf16<1><<<dim3(768 / 128, 64), 256, 0, stream>>>(
      (const void*)aoW, projwT, proj_b, nullptr, nullptr, nullptr,
      mask_f, psum, pmax, 8192);

  pool_stage2<<<dim3(3, B_), 256, 0, stream>>>(psum, pmax, pcnt, (float*)d_out);
}

// Round 7
// 283.908 us; speedup vs baseline: 1.1501x; 1.1501x over previous
//
#include <hip/hip_runtime.h>
#include <hip/hip_bf16.h>

typedef __attribute__((ext_vector_type(8))) short short8v;
typedef __attribute__((ext_vector_type(4))) float f32x4;

constexpr int B_  = 8;
constexpr int NH  = 12;
constexpr int DIM = 768;
constexpr int HD  = 64;
constexpr int N_  = 1025;
constexpr int NSP = 1024;
constexpr int K3  = 2304;
constexpr int KROWS = 1088;  // padded K rows (zeros past 1024), 34 tiles
constexpr int VT    = 34;    // kv tiles; V stored [bh][VT][64][32]
constexpr int CTN   = 1088;  // ct table length

// ---- workspace byte offsets ----
constexpr size_t OFF_MASK  = 0;
constexpr size_t OFF_PC    = 49152;
constexpr size_t OFF_QKVWT = 65536;
constexpr size_t OFF_PROJWT= OFF_QKVWT + (size_t)K3*768*2;
constexpr size_t OFF_Q     = OFF_PROJWT + (size_t)768*768*2;
constexpr size_t OFF_K     = OFF_Q + (size_t)B_*NH*N_*HD*2;
constexpr size_t K_BYTES   = (size_t)B_*NH*KROWS*HD*2;
constexpr size_t OFF_V     = OFF_K + K_BYTES;
constexpr size_t V_BYTES   = (size_t)B_*NH*VT*64*32*2;
constexpr size_t OFF_AO    = OFF_V + V_BYTES;
constexpr size_t OFF_PS    = OFF_AO + (size_t)8192*768*2;
constexpr size_t OFF_PM    = OFF_PS + 64*768*4;
constexpr size_t OFF_XB    = OFF_PM + 64*768*4;       // x bf16 [8320][768]

__device__ inline float b2f(unsigned short u) {
  union { unsigned int ui; float f; } x; x.ui = ((unsigned int)u) << 16; return x.f;
}
__device__ inline unsigned short f2b(float f) {
  union { float f; unsigned int u; } x; x.f = f;
  unsigned int r = x.u + 0x7FFFu + ((x.u >> 16) & 1u);
  return (unsigned short)(r >> 16);
}
__device__ inline unsigned int cvtpk(float lo, float hi) {
  unsigned int r;
  asm("v_cvt_pk_bf16_f32 %0, %1, %2" : "=v"(r) : "v"(lo), "v"(hi));
  return r;
}
__device__ inline short8v pack8(float4 lo, float4 hi) {
  union { unsigned int u[4]; short8v s; } r;
  r.u[0] = cvtpk(lo.x, lo.y); r.u[1] = cvtpk(lo.z, lo.w);
  r.u[2] = cvtpk(hi.x, hi.y); r.u[3] = cvtpk(hi.z, hi.w);
  return r.s;
}
__device__ inline float fexp2(float x) {
  float r;
  asm("v_exp_f32 %0, %1" : "=v"(r) : "v"(x));
  return r;
}
__device__ inline void gload16(const void* g, void* l) {
  __builtin_amdgcn_global_load_lds(
      (const __attribute__((address_space(1))) void*)g,
      (__attribute__((address_space(3))) void*)l, 16, 0, 0);
}

// ---------------- prep: pad K/V + mask convert + per-b count ----------------
__global__ __launch_bounds__(256) void prep(
    const unsigned char* __restrict__ mraw, float* __restrict__ mask_f,
    float* __restrict__ pcnt, unsigned short* __restrict__ kW,
    unsigned short* __restrict__ vW)
{
  const int g = blockIdx.x, t = threadIdx.x;
  if (g < 96) {
    unsigned short* kbase = kW + (size_t)g * KROWS * HD + 1025 * HD;
    for (int i = t; i < 63 * 64; i += 256) kbase[i] = 0;
    unsigned short* v32 = vW + ((size_t)g * VT + 32) * 2048;
    for (int i = t; i < 64 * 31; i += 256) {
      const int d = i / 31, c = i - d * 31;
      v32[d * 32 + 1 + c] = 0;
    }
    unsigned short* v33 = vW + ((size_t)g * VT + 33) * 2048;
    for (int i = t; i < 2048; i += 256) v33[i] = 0;
    return;
  }
  __shared__ int flags[2];
  __shared__ float cnt8[8];
  if (t < 2) flags[t] = 0;
  if (t < 8) cnt8[t] = 0.f;
  __syncthreads();
  const int n = B_ * N_;
  int f1 = 0, f0 = 0;
  for (int i = t; i < n; i += 256) {
    unsigned char vv = mraw[i];
    if (vv) { int m = i & 3; if (m == 1) f1 = 1; if (m == 0) f0 = 1; }
  }
  if (f1) atomicOr(&flags[0], 1);
  if (f0) atomicOr(&flags[1], 1);
  __syncthreads();
  const bool isBool = flags[0] != 0;
  const bool isInt  = !isBool && (flags[1] != 0);
  for (int i = t; i < n; i += 256) {
    float v;
    if (isBool)     v = mraw[i] ? 1.f : 0.f;
    else if (isInt) v = ((const int*)mraw)[i] ? 1.f : 0.f;
    else            v = ((const float*)mraw)[i];
    mask_f[i] = v;
    const int b = i / 1025, nn = i - b * 1025;
    if (nn > 0) atomicAdd(&cnt8[b], v);
  }
  __syncthreads();
  if (t < 8) pcnt[t] = cnt8[t];
}

// ---------------- f32 -> bf16 elementwise convert ----------------
__global__ __launch_bounds__(256) void cvt_f32_bf16(
    const float* __restrict__ in, unsigned short* __restrict__ out, int n4) {
  const int stride = gridDim.x * blockDim.x;
  for (int i = blockIdx.x * blockDim.x + threadIdx.x; i < n4; i += stride) {
    float4 v = *(const float4*)&in[i * 4];
    ushort4 u;
    u.x = f2b(v.x); u.y = f2b(v.y); u.z = f2b(v.z); u.w = f2b(v.w);
    *(ushort4*)&out[i * 4] = u;
  }
}

// ---------------- combined weight transpose f32[K][N] -> bf16[N][768] ------
__global__ void transpose_cvt2(const float* __restrict__ qkv_w,
                               const float* __restrict__ proj_w,
                               unsigned short* __restrict__ qkvwT,
                               unsigned short* __restrict__ projwT)
{
  __shared__ float tile[32][33];
  const int bx = blockIdx.x, by = blockIdx.y;
  const float* in; unsigned short* out; int N, n0;
  if (bx < 72) { in = qkv_w;  out = qkvwT;  N = K3;  n0 = bx * 32; }
  else         { in = proj_w; out = projwT; N = 768; n0 = (bx - 72) * 32; }
  const int tx = threadIdx.x, ty = threadIdx.y;
  tile[ty][tx] = in[(size_t)(by * 32 + ty) * N + n0 + tx];
  __syncthreads();
  out[(size_t)(n0 + ty) * 768 + by * 32 + tx] = f2b(tile[tx][ty]);
}

// ---------------- bf16 MFMA GEMM, global_load_lds double-buffered ----------
// 128x128 tile, BK=32, linear LDS [128][32], 4 gload_lds dwordx4/thread/step.
// MODE 0: A=xb, epilogue scatters q/k/v.  MODE 1: A=aoW, fused pooling.
template<int MODE>
__global__ __launch_bounds__(256) void gemm_bf16(
    const unsigned short* __restrict__ A, const unsigned short* __restrict__ BT,
    const float* __restrict__ bias,
    unsigned short* __restrict__ qo, unsigned short* __restrict__ ko,
    unsigned short* __restrict__ vo,
    const float* __restrict__ mask_f, float* __restrict__ psum,
    float* __restrict__ pmax, int M)
{
  __shared__ unsigned short As[2][128 * 32];
  __shared__ unsigned short Bs[2][128 * 32];
  __shared__ float Ms[128];
  const int t = threadIdx.x;
  const int l = t & 63, w = t >> 6;
  const int lg16 = l >> 4, lm16 = l & 15;
  const int wr = w >> 1, wc = w & 1;
  const int m0 = blockIdx.y * 128, n0 = blockIdx.x * 128;

  if (MODE == 1 && t < 128) {
    const int b0 = m0 >> 10, nr = m0 & 1023;
    Ms[t] = mask_f[b0 * N_ + 1 + nr + t];
  }

  f32x4 acc[4][4];
#pragma unroll
  for (int i = 0; i < 4; ++i)
#pragma unroll
    for (int j = 0; j < 4; ++j) acc[i][j] = (f32x4){0.f, 0.f, 0.f, 0.f};

  // staging chunk map: chunk c in [0,512): row=c>>2, 8-elem quad q=c&3
  const int row0 = t >> 2, qq = (t & 3) * 8;
  const unsigned short* Asrc0 = A + (size_t)(m0 + row0) * 768 + qq;
  const unsigned short* Asrc1 = A + (size_t)(m0 + row0 + 64) * 768 + qq;
  const unsigned short* Bsrc0 = BT + (size_t)(n0 + row0) * 768 + qq;
  const unsigned short* Bsrc1 = BT + (size_t)(n0 + row0 + 64) * 768 + qq;

#define STAGE(bi, k0)                                                    \
  do {                                                                   \
    gload16(Asrc0 + (k0), (char*)&As[bi][0] + w * 1024);                 \
    gload16(Asrc1 + (k0), (char*)&As[bi][0] + 4096 + w * 1024);          \
    gload16(Bsrc0 + (k0), (char*)&Bs[bi][0] + w * 1024);                 \
    gload16(Bsrc1 + (k0), (char*)&Bs[bi][0] + 4096 + w * 1024);          \
  } while (0)

  STAGE(0, 0);
  asm volatile("s_waitcnt vmcnt(0)" ::: "memory");
  __builtin_amdgcn_s_barrier();

#pragma unroll
  for (int kk = 0; kk < 24; ++kk) {
    const int cur = kk & 1;
    if (kk < 23) STAGE(cur ^ 1, (kk + 1) * 32);
    short8v af[4], bf4[4];
#pragma unroll
    for (int mi = 0; mi < 4; ++mi)
      af[mi] = *(const short8v*)&As[cur][(wr * 64 + mi * 16 + lm16) * 32 + lg16 * 8];
#pragma unroll
    for (int ni = 0; ni < 4; ++ni)
      bf4[ni] = *(const short8v*)&Bs[cur][(wc * 64 + ni * 16 + lm16) * 32 + lg16 * 8];
#pragma unroll
    for (int mi = 0; mi < 4; ++mi)
#pragma unroll
      for (int ni = 0; ni < 4; ++ni)
        acc[mi][ni] = __builtin_amdgcn_mfma_f32_16x16x32_bf16(
            af[mi], bf4[ni], acc[mi][ni], 0, 0, 0);
    asm volatile("s_waitcnt vmcnt(0)" ::: "memory");
    __builtin_amdgcn_s_barrier();
  }
#undef STAGE

  if (MODE == 1) {
    // ---- fused pooling epilogue ----
    __syncthreads();
    float* sred = (float*)&As[0][0];   // [2][128]
    float* xred = sred + 256;          // [2][128]
#pragma unroll
    for (int ni = 0; ni < 4; ++ni) {
      const int cidx = wc * 64 + ni * 16 + lm16;
      const float bv = bias[n0 + cidx];
      float s = 0.f, xm = -3.402823466e+38f;
#pragma unroll
      for (int mi = 0; mi < 4; ++mi)
#pragma unroll
        for (int r = 0; r < 4; ++r) {
          const float v = acc[mi][ni][r] + bv;
          const float m = Ms[wr * 64 + mi * 16 + lg16 * 4 + r];
          s = fmaf(v, m, s);
          xm = fmaxf(xm, v);
        }
      s += __shfl_xor(s, 16);
      s += __shfl_xor(s, 32);
      xm = fmaxf(xm, __shfl_xor(xm, 16));
      xm = fmaxf(xm, __shfl_xor(xm, 32));
      if (lg16 == 0) {
        sred[wr * 128 + cidx] = s;
        xred[wr * 128 + cidx] = xm;
      }
    }
    __syncthreads();
    if (t < 128) {
      const float s  = sred[t] + sred[128 + t];
      const float xm = fmaxf(xred[t], xred[128 + t]);
      psum[(size_t)blockIdx.y * 768 + n0 + t] = s;
      pmax[(size_t)blockIdx.y * 768 + n0 + t] = xm;
    }
  } else {
#pragma unroll
    for (int mi = 0; mi < 4; ++mi) {
      const int r0 = m0 + wr * 64 + mi * 16 + lg16 * 4;
#pragma unroll
      for (int ni = 0; ni < 4; ++ni) {
        const int col = n0 + wc * 64 + ni * 16 + lm16;
        const int which = col / 768;
        const int rem = col - which * 768;
        const int head = rem >> 6, d = rem & 63;
        const float bv = bias[col];
#pragma unroll
        for (int r = 0; r < 4; ++r) {
          const int grow = r0 + r;
          if (grow >= M) continue;
          const int b = grow / 1025;
          const int n = grow - b * 1025;
          const unsigned short val = f2b(acc[mi][ni][r] + bv);
          const int bh = b * NH + head;
          if (which == 0)
            qo[((size_t)bh * N_ + n) * HD + d] = val;
          else if (which == 1)
            ko[((size_t)bh * KROWS + n) * HD + d] = val;
          else
            vo[((size_t)bh * VT + (n >> 5)) * 2048 + d * 32 + (n & 31)] = val;
        }
      }
    }
  }
}

// ---------------- MFMA flash attention v6 (software-pipelined) ----------------
// 4 waves/block, wave owns 16 q rows. qt-major work order (same-CU blocks
// share ~3 heads -> K/V tiles L1-resident). Iter kt: softmax+PV(kt) runs in
// parallel with QK(kt+1); K prefetched one tile ahead in regs.
__global__ __launch_bounds__(256) void attn_mfma(
    const unsigned short* __restrict__ qp, const unsigned short* __restrict__ kp,
    const unsigned short* __restrict__ vp, const float* __restrict__ mask_f,
    const float* __restrict__ rph, const float* __restrict__ rpw,
    unsigned short* __restrict__ ao)
{
  const int bid = blockIdx.x;
  const int xcd = bid & 7, wx = bid >> 3;     // wx in [0,192)
  const int qt = wx / 12, hl = wx - qt * 12;  // qt-major within XCD
  const int bh = xcd * 12 + hl;
  const int b = bh / NH, head = bh - b * NH;

  const int t = threadIdx.x, l = t & 63, w = t >> 6;
  const int lg16 = l >> 4, lm16 = l & 15;
  const int w16 = w * 16;
  constexpr float L2E = 1.44269504f;
  constexpr float SCL = 0.125f * L2E;
  constexpr float MCOL = -1.44269504e9f;
  constexpr float THR_L = 5.77f;

  __shared__ float bh_lds[64][34];
  __shared__ float ct_lds[CTN];
  __shared__ unsigned int arena[3072];            // bw2 [64][48] f32 | p_lds
  float (*bw2_lds)[48] = (float(*)[48])arena;
  unsigned int (*p_lds)[16 * 20] = (unsigned int(*)[16 * 20])arena;

  const unsigned short* qb = qp + (size_t)bh * N_ * HD;
  const unsigned short* kb = kp + (size_t)bh * KROWS * HD;
  const unsigned short* vb = vp + (size_t)bh * VT * 2048;
  const int q0 = qt * 64 + w16;

  for (int i = t; i < CTN; i += 256)
    ct_lds[i] = (i < N_) ? (MCOL * (1.f - mask_f[b * N_ + i])) : -2e30f;

  short8v qf[2];
#pragma unroll
  for (int kk = 0; kk < 2; ++kk)
    qf[kk] = *(const short8v*)&qb[(size_t)(1 + q0 + lm16) * HD + kk * 32 + lg16 * 8];

  // ---- rel-pos bias tables via MFMA ----
  {
    const int hq = q0 >> 5, wq0 = q0 & 31;
    const f32x4 z4 = (f32x4){0.f, 0.f, 0.f, 0.f};
    f32x4 sbh[2] = {z4, z4};
    f32x4 sbw[3] = {z4, z4, z4};
#pragma unroll
    for (int nt = 0; nt < 2; ++nt) {
      const float* rp = &rph[(size_t)(hq + 31 - (nt * 16 + lm16)) * HD];
#pragma unroll
      for (int kk = 0; kk < 2; ++kk) {
        float4 lo = *(const float4*)&rp[kk * 32 + lg16 * 8];
        float4 hi = *(const float4*)&rp[kk * 32 + lg16 * 8 + 4];
        sbh[nt] = __builtin_amdgcn_mfma_f32_16x16x32_bf16(
            pack8(lo, hi), qf[kk], sbh[nt], 0, 0, 0);
      }
    }
#pragma unroll
    for (int nt = 0; nt < 3; ++nt) {
      int u = wq0 + nt * 16 + lm16;
      u = u > 62 ? 62 : u;
      const float* rp = &rpw[(size_t)u * HD];
#pragma unroll
      for (int kk = 0; kk < 2; ++kk) {
        float4 lo = *(const float4*)&rp[kk * 32 + lg16 * 8];
        float4 hi = *(const float4*)&rp[kk * 32 + lg16 * 8 + 4];
        sbw[nt] = __builtin_amdgcn_mfma_f32_16x16x32_bf16(
            pack8(lo, hi), qf[kk], sbw[nt], 0, 0, 0);
      }
    }
#pragma unroll
    for (int nt = 0; nt < 2; ++nt)
#pragma unroll
      for (int reg = 0; reg < 4; ++reg)
        bh_lds[w16 + lm16][nt * 16 + lg16 * 4 + reg] = sbh[nt][reg] * L2E;
    if (lg16 == 0) {
      bh_lds[w16 + lm16][32] = 0.f;
      bh_lds[w16 + lm16][33] = 0.f;
    }
#pragma unroll
    for (int nt = 0; nt < 3; ++nt)
#pragma unroll
      for (int reg = 0; reg < 4; ++reg)
        bw2_lds[w16 + lm16][nt * 16 + lg16 * 4 + reg] = sbw[nt][reg] * L2E;
  }
  __syncthreads();

  const float mi_s = mask_f[b * N_ + 1 + q0 + lm16];
  const bool mzero = (mi_s == 0.f);
  float bwv[2][4];
#pragma unroll
  for (int nt = 0; nt < 2; ++nt)
#pragma unroll
    for (int reg = 0; reg < 4; ++reg) {
      const int kw = (lg16 * 4 + reg + 16 * nt + 31) & 31;
      bwv[nt][reg] = bw2_lds[w16 + lm16][31 + lm16 - kw];
    }
  const float bw31v = bw2_lds[w16 + lm16][lm16];
  __syncthreads();   // arena handoff: bw2 reads done before p_lds writes

  float m_lm = -1e30f, bh_prev = 0.f;
  f32x4 oacc[4];
#pragma unroll
  for (int dt = 0; dt < 4; ++dt) oacc[dt] = (f32x4){0.f, 0.f, 0.f, 0.f};
  f32x4 lacc = (f32x4){0.f, 0.f, 0.f, 0.f};
  short8v ones;
#pragma unroll
  for (int j = 0; j < 8; ++j) ones[j] = (short)0x3F80;

  unsigned int* pw = &p_lds[w][lm16 * 20 + lg16 * 2];
  const unsigned int* pr = &p_lds[w][lm16 * 20 + lg16 * 4];

  const f32x4 z4 = (f32x4){0.f, 0.f, 0.f, 0.f};
  const char* kpre = (const char*)kb + lm16 * 128 + lg16 * 16;
  const char* vcur = (const char*)vb + lm16 * 64 + lg16 * 16;

  // prologue: S(tile0) and K(tile1) in regs
  short8v kA0 = *(const short8v*)(kpre);
  short8v kA1 = *(const short8v*)(kpre + 64);
  short8v kB0 = *(const short8v*)(kpre + 2048);
  short8v kB1 = *(const short8v*)(kpre + 2112);
  kpre += 4096;
  f32x4 spA = z4, spB = z4;
  spA = __builtin_amdgcn_mfma_f32_16x16x32_bf16(kA0, qf[0], spA, 0, 0, 0);
  spA = __builtin_amdgcn_mfma_f32_16x16x32_bf16(kA1, qf[1], spA, 0, 0, 0);
  spB = __builtin_amdgcn_mfma_f32_16x16x32_bf16(kB0, qf[0], spB, 0, 0, 0);
  spB = __builtin_amdgcn_mfma_f32_16x16x32_bf16(kB1, qf[1], spB, 0, 0, 0);
  kA0 = *(const short8v*)(kpre);
  kA1 = *(const short8v*)(kpre + 64);
  kB0 = *(const short8v*)(kpre + 2048);
  kB1 = *(const short8v*)(kpre + 2112);
  kpre += 4096;

  for (int kt = 0; kt < 34; ++kt) {
    const f32x4 sA = spA, sB = spB;
    short8v vf0 = *(const short8v*)(vcur);
    short8v vf1 = *(const short8v*)(vcur + 1024);
    short8v vf2 = *(const short8v*)(vcur + 2048);
    short8v vf3 = *(const short8v*)(vcur + 3072);
    vcur += 4096;

    // ---- logits (log2 domain), tile kt ----
    const float bh_k = bh_lds[w16 + lm16][kt];
    const float edgebias = (kt == 0 || kt >= 32) ? 0.f : (bh_prev + bw31v);
    bh_prev = bh_k;
    f32x4 ct0 = *(const f32x4*)&ct_lds[kt * 32 + lg16 * 4];
    f32x4 ct1 = *(const f32x4*)&ct_lds[kt * 32 + 16 + lg16 * 4];
    float lg_[2][4];
#pragma unroll
    for (int reg = 0; reg < 4; ++reg) {
      float bias20 = bh_k + bwv[0][reg];
      if (reg == 0) bias20 = (lg16 == 0) ? edgebias : bias20;
      const float ec0 = mzero ? fminf(ct0[reg], MCOL) : ct0[reg];
      lg_[0][reg] = fmaf(SCL, sA[reg], bias20 + ec0);
      const float bias21 = bh_k + bwv[1][reg];
      const float ec1 = mzero ? fminf(ct1[reg], MCOL) : ct1[reg];
      lg_[1][reg] = fmaf(SCL, sB[reg], bias21 + ec1);
    }
    // ---- online softmax, defer-max ----
    float tm = fmaxf(fmaxf(fmaxf(lg_[0][0], lg_[0][1]), fmaxf(lg_[0][2], lg_[0][3])),
                     fmaxf(fmaxf(lg_[1][0], lg_[1][1]), fmaxf(lg_[1][2], lg_[1][3])));
    tm = fmaxf(tm, __shfl_xor(tm, 16));
    tm = fmaxf(tm, __shfl_xor(tm, 32));
    if (__any(tm > m_lm + THR_L)) {
      const float nm = fmaxf(m_lm, tm);
      const float rf = fexp2(m_lm - nm);
      m_lm = nm;
      float rfr[4];
#pragma unroll
      for (int reg = 0; reg < 4; ++reg) rfr[reg] = __shfl(rf, lg16 * 4 + reg);
#pragma unroll
      for (int dt = 0; dt < 4; ++dt)
#pragma unroll
        for (int reg = 0; reg < 4; ++reg) oacc[dt][reg] *= rfr[reg];
#pragma unroll
      for (int reg = 0; reg < 4; ++reg) lacc[reg] *= rfr[reg];
    }
    float p[2][4];
#pragma unroll
    for (int nt = 0; nt < 2; ++nt)
#pragma unroll
      for (int reg = 0; reg < 4; ++reg)
        p[nt][reg] = fexp2(lg_[nt][reg] - m_lm);
    pw[0] = cvtpk(p[0][0], p[0][1]);
    pw[1] = cvtpk(p[0][2], p[0][3]);
    pw[8] = cvtpk(p[1][0], p[1][1]);
    pw[9] = cvtpk(p[1][2], p[1][3]);

    // ---- QK for tile kt+1 (independent of softmax above) ----
    if (kt < 33) {
      f32x4 nA = z4, nB = z4;
      nA = __builtin_amdgcn_mfma_f32_16x16x32_bf16(kA0, qf[0], nA, 0, 0, 0);
      nA = __builtin_amdgcn_mfma_f32_16x16x32_bf16(kA1, qf[1], nA, 0, 0, 0);
      nB = __builtin_amdgcn_mfma_f32_16x16x32_bf16(kB0, qf[0], nB, 0, 0, 0);
      nB = __builtin_amdgcn_mfma_f32_16x16x32_bf16(kB1, qf[1], nB, 0, 0, 0);
      spA = nA; spB = nB;
    }
    // ---- prefetch K tile kt+2 ----
    if (kt < 32) {
      kA0 = *(const short8v*)(kpre);
      kA1 = *(const short8v*)(kpre + 64);
      kB0 = *(const short8v*)(kpre + 2048);
      kB1 = *(const short8v*)(kpre + 2112);
      kpre += 4096;
    }
    // ---- PV ----
    const short8v pa = *(const short8v*)pr;
    oacc[0] = __builtin_amdgcn_mfma_f32_16x16x32_bf16(pa, vf0, oacc[0], 0, 0, 0);
    oacc[1] = __builtin_amdgcn_mfma_f32_16x16x32_bf16(pa, vf1, oacc[1], 0, 0, 0);
    oacc[2] = __builtin_amdgcn_mfma_f32_16x16x32_bf16(pa, vf2, oacc[2], 0, 0, 0);
    oacc[3] = __builtin_amdgcn_mfma_f32_16x16x32_bf16(pa, vf3, oacc[3], 0, 0, 0);
    lacc = __builtin_amdgcn_mfma_f32_16x16x32_bf16(pa, ones, lacc, 0, 0, 0);
  }

  // ---- epilogue ----
  float inv[4];
#pragma unroll
  for (int reg = 0; reg < 4; ++reg) inv[reg] = 1.f / lacc[reg];
#pragma unroll
  for (int dt = 0; dt < 4; ++dt)
#pragma unroll
    for (int reg = 0; reg < 4; ++reg) {
      const int nsp = q0 + lg16 * 4 + reg;
      const float val = oacc[dt][reg] * inv[reg];
      ao[((size_t)(b * NSP + nsp)) * DIM + head * HD + dt * 16 + lm16] = f2b(val);
    }
}

// ---------------- final pooling reduce ----------------
__global__ __launch_bounds__(256) void pool_stage2(
    const float* __restrict__ psum, const float* __restrict__ pmax,
    const float* __restrict__ pcnt, float* __restrict__ out)
{
  const int b = blockIdx.y;
  const int c = blockIdx.x * 256 + threadIdx.x;
  float s = 0.f, mx = -3.402823466e+38f;
#pragma unroll
  for (int z = 0; z < 8; ++z) {
    s  += psum[(size_t)(b * 8 + z) * 768 + c];
    mx  = fmaxf(mx, pmax[(size_t)(b * 8 + z) * 768 + c]);
  }
  const float cnt = pcnt[b];
  out[b * 1536 + c]       = s / (cnt + 1e-7f);
  out[b * 1536 + 768 + c] = mx;
}

// ---------------- launch ----------------
extern "C" void kernel_launch(void* const* d_in, const int* in_sizes, int n_in,
                              void* d_out, int out_size, void* d_ws, size_t ws_size,
                              hipStream_t stream) {
  const float* x      = (const float*)d_in[0];
  const unsigned char* mraw = (const unsigned char*)d_in[1];
  const float* qkv_w  = (const float*)d_in[2];
  const float* qkv_b  = (const float*)d_in[3];
  const float* proj_w = (const float*)d_in[4];
  const float* proj_b = (const float*)d_in[5];
  const float* rph    = (const float*)d_in[6];
  const float* rpw    = (const float*)d_in[7];

  char* ws = (char*)d_ws;
  float*          mask_f = (float*)(ws + OFF_MASK);
  float*          pcnt   = (float*)(ws + OFF_PC);
  unsigned short* qkvwT  = (unsigned short*)(ws + OFF_QKVWT);
  unsigned short* projwT = (unsigned short*)(ws + OFF_PROJWT);
  unsigned short* qW     = (unsigned short*)(ws + OFF_Q);
  unsigned short* kW     = (unsigned short*)(ws + OFF_K);
  unsigned short* vW     = (unsigned short*)(ws + OFF_V);
  unsigned short* aoW    = (unsigned short*)(ws + OFF_AO);
  float*          psum   = (float*)(ws + OFF_PS);
  float*          pmax   = (float*)(ws + OFF_PM);
  unsigned short* xb     = (unsigned short*)(ws + OFF_XB);

  prep<<<97, 256, 0, stream>>>(mraw, mask_f, pcnt, kW, vW);
  transpose_cvt2<<<dim3(96, 24), dim3(32, 32), 0, stream>>>(
      qkv_w, proj_w, qkvwT, projwT);
  cvt_f32_bf16<<<2048, 256, 0, stream>>>(x, xb, 8200 * 768 / 4);

  gemm_bf16<0><<<dim3(K3 / 128, 65), 256, 0, stream>>>(
      xb, qkvwT, qkv_b, qW, kW, vW, nullptr, nullptr, nullptr, 8200);

  attn_mfma<<<1536, 256, 0, stream>>>(qW, kW, vW, mask_f, rph, rpw, aoW);

  gemm_bf16<1><<<dim3(768 / 128, 64), 256, 0, stream>>>(
      aoW, projwT, proj_b, nullptr, nullptr, nullptr,
      mask_f, psum, pmax, 8192);

  pool_stage2<<<dim3(3, B_), 256, 0, stream>>>(psum, pmax, pcnt, (float*)d_out);
}

// Round 8
// 208.586 us; speedup vs baseline: 1.5654x; 1.3611x over previous
//
#include <hip/hip_runtime.h>
#include <hip/hip_bf16.h>

typedef __attribute__((ext_vector_type(8))) short short8v;
typedef __attribute__((ext_vector_type(4))) float f32x4;
typedef __attribute__((ext_vector_type(16))) float f32x16;

constexpr int B_  = 8;
constexpr int NH  = 12;
constexpr int DIM = 768;
constexpr int HD  = 64;
constexpr int N_  = 1025;
constexpr int NSP = 1024;
constexpr int K3  = 2304;
constexpr int KROWS = 1088;  // padded K rows (zeros past 1024), 34 tiles
constexpr int VT    = 34;    // kv tiles; V stored [bh][VT][64][32]

// ---- workspace byte offsets ----
constexpr size_t OFF_MASK  = 0;
constexpr size_t OFF_PC    = 49152;
constexpr size_t OFF_QKVWT = 65536;
constexpr size_t OFF_PROJWT= OFF_QKVWT + (size_t)K3*768*2;
constexpr size_t OFF_Q     = OFF_PROJWT + (size_t)768*768*2;
constexpr size_t OFF_K     = OFF_Q + (size_t)B_*NH*N_*HD*2;
constexpr size_t K_BYTES   = (size_t)B_*NH*KROWS*HD*2;
constexpr size_t OFF_V     = OFF_K + K_BYTES;
constexpr size_t V_BYTES   = (size_t)B_*NH*VT*64*32*2;
constexpr size_t OFF_AO    = OFF_V + V_BYTES;
constexpr size_t OFF_PS    = OFF_AO + (size_t)8192*768*2;
constexpr size_t OFF_PM    = OFF_PS + 64*768*4;
constexpr size_t OFF_XB    = OFF_PM + 64*768*4;       // x bf16

__device__ inline float b2f(unsigned short u) {
  union { unsigned int ui; float f; } x; x.ui = ((unsigned int)u) << 16; return x.f;
}
__device__ inline unsigned short f2b(float f) {
  union { float f; unsigned int u; } x; x.f = f;
  unsigned int r = x.u + 0x7FFFu + ((x.u >> 16) & 1u);
  return (unsigned short)(r >> 16);
}
__device__ inline unsigned int cvtpk(float lo, float hi) {
  unsigned int r;
  asm("v_cvt_pk_bf16_f32 %0, %1, %2" : "=v"(r) : "v"(lo), "v"(hi));
  return r;
}
__device__ inline short8v pack8(float4 lo, float4 hi) {
  union { unsigned int u[4]; short8v s; } r;
  r.u[0] = cvtpk(lo.x, lo.y); r.u[1] = cvtpk(lo.z, lo.w);
  r.u[2] = cvtpk(hi.x, hi.y); r.u[3] = cvtpk(hi.z, hi.w);
  return r.s;
}
__device__ inline float fexp2(float x) {
  float r;
  asm("v_exp_f32 %0, %1" : "=v"(r) : "v"(x));
  return r;
}
__device__ inline void plswap(unsigned int& a, unsigned int& b) {
  asm("v_permlane32_swap_b32 %0, %1" : "+v"(a), "+v"(b));
}
__device__ inline void gload16(const void* g, void* l) {
  __builtin_amdgcn_global_load_lds(
      (const __attribute__((address_space(1))) void*)g,
      (__attribute__((address_space(3))) void*)l, 16, 0, 0);
}

// ---------------- prep: pad K/V + mask convert + per-b count ----------------
__global__ __launch_bounds__(256) void prep(
    const unsigned char* __restrict__ mraw, float* __restrict__ mask_f,
    float* __restrict__ pcnt, unsigned short* __restrict__ kW,
    unsigned short* __restrict__ vW)
{
  const int g = blockIdx.x, t = threadIdx.x;
  if (g < 96) {
    unsigned short* kbase = kW + (size_t)g * KROWS * HD + 1025 * HD;
    for (int i = t; i < 63 * 64; i += 256) kbase[i] = 0;
    unsigned short* v32 = vW + ((size_t)g * VT + 32) * 2048;
    for (int i = t; i < 64 * 31; i += 256) {
      const int d = i / 31, c = i - d * 31;
      v32[d * 32 + 1 + c] = 0;
    }
    unsigned short* v33 = vW + ((size_t)g * VT + 33) * 2048;
    for (int i = t; i < 2048; i += 256) v33[i] = 0;
    return;
  }
  __shared__ int flags[2];
  __shared__ float cnt8[8];
  if (t < 2) flags[t] = 0;
  if (t < 8) cnt8[t] = 0.f;
  __syncthreads();
  const int n = B_ * N_;
  int f1 = 0, f0 = 0;
  for (int i = t; i < n; i += 256) {
    unsigned char vv = mraw[i];
    if (vv) { int m = i & 3; if (m == 1) f1 = 1; if (m == 0) f0 = 1; }
  }
  if (f1) atomicOr(&flags[0], 1);
  if (f0) atomicOr(&flags[1], 1);
  __syncthreads();
  const bool isBool = flags[0] != 0;
  const bool isInt  = !isBool && (flags[1] != 0);
  for (int i = t; i < n; i += 256) {
    float v;
    if (isBool)     v = mraw[i] ? 1.f : 0.f;
    else if (isInt) v = ((const int*)mraw)[i] ? 1.f : 0.f;
    else            v = ((const float*)mraw)[i];
    mask_f[i] = v;
    const int b = i / 1025, nn = i - b * 1025;
    if (nn > 0) atomicAdd(&cnt8[b], v);
  }
  __syncthreads();
  if (t < 8) pcnt[t] = cnt8[t];
}

// ---------------- f32 -> bf16 elementwise convert ----------------
__global__ __launch_bounds__(256) void cvt_f32_bf16(
    const float* __restrict__ in, unsigned short* __restrict__ out, int n4) {
  const int stride = gridDim.x * blockDim.x;
  for (int i = blockIdx.x * blockDim.x + threadIdx.x; i < n4; i += stride) {
    float4 v = *(const float4*)&in[i * 4];
    ushort4 u;
    u.x = f2b(v.x); u.y = f2b(v.y); u.z = f2b(v.z); u.w = f2b(v.w);
    *(ushort4*)&out[i * 4] = u;
  }
}

// ---------------- combined weight transpose f32[K][N] -> bf16[N][768] ------
__global__ void transpose_cvt2(const float* __restrict__ qkv_w,
                               const float* __restrict__ proj_w,
                               unsigned short* __restrict__ qkvwT,
                               unsigned short* __restrict__ projwT)
{
  __shared__ float tile[32][33];
  const int bx = blockIdx.x, by = blockIdx.y;
  const float* in; unsigned short* out; int N, n0;
  if (bx < 72) { in = qkv_w;  out = qkvwT;  N = K3;  n0 = bx * 32; }
  else         { in = proj_w; out = projwT; N = 768; n0 = (bx - 72) * 32; }
  const int tx = threadIdx.x, ty = threadIdx.y;
  tile[ty][tx] = in[(size_t)(by * 32 + ty) * N + n0 + tx];
  __syncthreads();
  out[(size_t)(n0 + ty) * 768 + by * 32 + tx] = f2b(tile[tx][ty]);
}

// ---------------- bf16 MFMA GEMM, global_load_lds double-buffered ----------
template<int MODE>
__global__ __launch_bounds__(256) void gemm_bf16(
    const unsigned short* __restrict__ A, const unsigned short* __restrict__ BT,
    const float* __restrict__ bias,
    unsigned short* __restrict__ qo, unsigned short* __restrict__ ko,
    unsigned short* __restrict__ vo,
    const float* __restrict__ mask_f, float* __restrict__ psum,
    float* __restrict__ pmax, int M)
{
  __shared__ unsigned short As[2][128 * 32];
  __shared__ unsigned short Bs[2][128 * 32];
  __shared__ float Ms[128];
  const int t = threadIdx.x;
  const int l = t & 63, w = t >> 6;
  const int lg16 = l >> 4, lm16 = l & 15;
  const int wr = w >> 1, wc = w & 1;
  const int m0 = blockIdx.y * 128, n0 = blockIdx.x * 128;

  if (MODE == 1 && t < 128) {
    const int b0 = m0 >> 10, nr = m0 & 1023;
    Ms[t] = mask_f[b0 * N_ + 1 + nr + t];
  }

  f32x4 acc[4][4];
#pragma unroll
  for (int i = 0; i < 4; ++i)
#pragma unroll
    for (int j = 0; j < 4; ++j) acc[i][j] = (f32x4){0.f, 0.f, 0.f, 0.f};

  const int row0 = t >> 2, qq = (t & 3) * 8;
  const unsigned short* Asrc0 = A + (size_t)(m0 + row0) * 768 + qq;
  const unsigned short* Asrc1 = A + (size_t)(m0 + row0 + 64) * 768 + qq;
  const unsigned short* Bsrc0 = BT + (size_t)(n0 + row0) * 768 + qq;
  const unsigned short* Bsrc1 = BT + (size_t)(n0 + row0 + 64) * 768 + qq;

#define STAGE(bi, k0)                                                    \
  do {                                                                   \
    gload16(Asrc0 + (k0), (char*)&As[bi][0] + w * 1024);                 \
    gload16(Asrc1 + (k0), (char*)&As[bi][0] + 4096 + w * 1024);          \
    gload16(Bsrc0 + (k0), (char*)&Bs[bi][0] + w * 1024);                 \
    gload16(Bsrc1 + (k0), (char*)&Bs[bi][0] + 4096 + w * 1024);          \
  } while (0)

  STAGE(0, 0);
  asm volatile("s_waitcnt vmcnt(0)" ::: "memory");
  __builtin_amdgcn_s_barrier();

#pragma unroll
  for (int kk = 0; kk < 24; ++kk) {
    const int cur = kk & 1;
    if (kk < 23) STAGE(cur ^ 1, (kk + 1) * 32);
    short8v af[4], bf4[4];
#pragma unroll
    for (int mi = 0; mi < 4; ++mi)
      af[mi] = *(const short8v*)&As[cur][(wr * 64 + mi * 16 + lm16) * 32 + lg16 * 8];
#pragma unroll
    for (int ni = 0; ni < 4; ++ni)
      bf4[ni] = *(const short8v*)&Bs[cur][(wc * 64 + ni * 16 + lm16) * 32 + lg16 * 8];
#pragma unroll
    for (int mi = 0; mi < 4; ++mi)
#pragma unroll
      for (int ni = 0; ni < 4; ++ni)
        acc[mi][ni] = __builtin_amdgcn_mfma_f32_16x16x32_bf16(
            af[mi], bf4[ni], acc[mi][ni], 0, 0, 0);
    asm volatile("s_waitcnt vmcnt(0)" ::: "memory");
    __builtin_amdgcn_s_barrier();
  }
#undef STAGE

  if (MODE == 1) {
    __syncthreads();
    float* sred = (float*)&As[0][0];
    float* xred = sred + 256;
#pragma unroll
    for (int ni = 0; ni < 4; ++ni) {
      const int cidx = wc * 64 + ni * 16 + lm16;
      const float bv = bias[n0 + cidx];
      float s = 0.f, xm = -3.402823466e+38f;
#pragma unroll
      for (int mi = 0; mi < 4; ++mi)
#pragma unroll
        for (int r = 0; r < 4; ++r) {
          const float v = acc[mi][ni][r] + bv;
          const float m = Ms[wr * 64 + mi * 16 + lg16 * 4 + r];
          s = fmaf(v, m, s);
          xm = fmaxf(xm, v);
        }
      s += __shfl_xor(s, 16);
      s += __shfl_xor(s, 32);
      xm = fmaxf(xm, __shfl_xor(xm, 16));
      xm = fmaxf(xm, __shfl_xor(xm, 32));
      if (lg16 == 0) {
        sred[wr * 128 + cidx] = s;
        xred[wr * 128 + cidx] = xm;
      }
    }
    __syncthreads();
    if (t < 128) {
      const float s  = sred[t] + sred[128 + t];
      const float xm = fmaxf(xred[t], xred[128 + t]);
      psum[(size_t)blockIdx.y * 768 + n0 + t] = s;
      pmax[(size_t)blockIdx.y * 768 + n0 + t] = xm;
    }
  } else {
#pragma unroll
    for (int mi = 0; mi < 4; ++mi) {
      const int r0 = m0 + wr * 64 + mi * 16 + lg16 * 4;
#pragma unroll
      for (int ni = 0; ni < 4; ++ni) {
        const int col = n0 + wc * 64 + ni * 16 + lm16;
        const int which = col / 768;
        const int rem = col - which * 768;
        const int head = rem >> 6, d = rem & 63;
        const float bv = bias[col];
#pragma unroll
        for (int r = 0; r < 4; ++r) {
          const int grow = r0 + r;
          if (grow >= M) continue;
          const int b = grow / 1025;
          const int n = grow - b * 1025;
          const unsigned short val = f2b(acc[mi][ni][r] + bv);
          const int bh = b * NH + head;
          if (which == 0)
            qo[((size_t)bh * N_ + n) * HD + d] = val;
          else if (which == 1)
            ko[((size_t)bh * KROWS + n) * HD + d] = val;
          else
            vo[((size_t)bh * VT + (n >> 5)) * 2048 + d * 32 + (n & 31)] = val;
        }
      }
    }
  }
}

// ---------------- MFMA flash attention v7: 32x32 MFMA, 32 q/wave ----------
// Lane holds col q=lane&31 of S^T -> softmax fully per-lane (1 shfl/iter),
// P->PV transpose via cvtpk + v_permlane32_swap (no LDS round-trip).
__global__ __launch_bounds__(256, 3) void attn_mfma(
    const unsigned short* __restrict__ qp, const unsigned short* __restrict__ kp,
    const unsigned short* __restrict__ vp, const float* __restrict__ mask_f,
    const float* __restrict__ rph, const float* __restrict__ rpw,
    unsigned short* __restrict__ ao)
{
  const int bid = blockIdx.x;
  const int xcd = bid & 7, wx = bid >> 3;        // 0..95
  const int qblk = wx / 12, hl = wx - qblk * 12;
  const int bh = xcd * 12 + hl;
  const int b = bh / NH, head = bh - b * NH;

  const int t = threadIdx.x, w = t >> 6, lane = t & 63;
  const int qi = lane & 31, h = lane >> 5;
  const int row = w * 32 + qi;
  constexpr float L2E = 1.44269504f;
  constexpr float SCL = 0.125f * L2E;
  constexpr float MCOL = -1.44269504e9f;
  constexpr float THR_L = 5.77f;

  __shared__ float bh_lds[128][37];        // [q][kh], *L2E; cols 32..34 = 0
  __shared__ float ct_lds[1088];           // column mask term *L2E
  __shared__ unsigned short T16[128][72];  // bw table (bf16); later O-transpose

  const unsigned short* qbp = qp + (size_t)bh * N_ * HD;
  const unsigned short* kbp = kp + (size_t)bh * KROWS * HD;
  const unsigned short* vbp = vp + (size_t)bh * VT * 2048;
  const int qw0 = qblk * 128 + w * 32;
  const int q = qw0 + qi;                  // spatial 0..1023

  for (int i = t; i < 1088; i += 256)
    ct_lds[i] = (i < N_) ? (MCOL * (1.f - mask_f[b * N_ + i])) : -2e30f;

  // Q fragments (B operand): n=q=lane&31, k = c*16 + h*8 + j
  short8v qf[4];
#pragma unroll
  for (int c = 0; c < 4; ++c)
    qf[c] = *(const short8v*)&qbp[(size_t)(1 + q) * HD + c * 16 + h * 8];

  // ---- rel-pos bias tables via 32x32 MFMA ----
  {
    const int hq = q >> 5;                 // constant per wave
    f32x16 sbh = {}, sb1 = {}, sb2 = {};
    const float* rh0 = rph + (size_t)(hq + 31 - qi) * HD + h * 8;
    const float* rw1 = rpw + (size_t)qi * HD + h * 8;
    const float* rw2 = rpw + (size_t)(qi < 31 ? 32 + qi : 62) * HD + h * 8;
#pragma unroll
    for (int c = 0; c < 4; ++c) {
      short8v a1 = pack8(*(const float4*)(rh0 + c * 16), *(const float4*)(rh0 + c * 16 + 4));
      sbh = __builtin_amdgcn_mfma_f32_32x32x16_bf16(a1, qf[c], sbh, 0, 0, 0);
      short8v a2 = pack8(*(const float4*)(rw1 + c * 16), *(const float4*)(rw1 + c * 16 + 4));
      sb1 = __builtin_amdgcn_mfma_f32_32x32x16_bf16(a2, qf[c], sb1, 0, 0, 0);
      short8v a3 = pack8(*(const float4*)(rw2 + c * 16), *(const float4*)(rw2 + c * 16 + 4));
      sb2 = __builtin_amdgcn_mfma_f32_32x32x16_bf16(a3, qf[c], sb2, 0, 0, 0);
    }
#pragma unroll
    for (int r = 0; r < 16; ++r) {
      const int kh = (r & 3) + 8 * (r >> 2) + 4 * h;
      bh_lds[row][kh]  = sbh[r] * L2E;
      T16[row][kh]      = f2b(sb1[r] * L2E);
      T16[row][kh + 32] = f2b(sb2[r] * L2E);
    }
    if (h == 0) {
      bh_lds[row][32] = 0.f; bh_lds[row][33] = 0.f; bh_lds[row][34] = 0.f;
    }
  }
  __syncthreads();

  // per-lane bw preload: slot r -> kv_local = (r&3)+8*(r>>2)+4h, kw=(kv-1)&31
  float bwv[16];
#pragma unroll
  for (int r = 0; r < 16; ++r) {
    const int kvS = (r & 3) + 8 * (r >> 2) + 4 * h;
    const int kw = (kvS + 31) & 31;
    bwv[r] = b2f(T16[row][qi - kw + 31]);
  }

  const float mi_s = mask_f[b * N_ + 1 + q];
  const bool mzero = (mi_s == 0.f);
  float m_lm = -1e30f, l_lane = 0.f;
  float bh_prev = -bwv[0];                 // kt=0 slot0 -> total bias 0 (cls)
  f32x16 oaccA = {}, oaccB = {};

  const char* kptr = (const char*)kbp + qi * 128 + h * 16;
  const char* vptr = (const char*)vbp + qi * 64 + h * 16;
  short8v kf[4], kfn[4];
#pragma unroll
  for (int c = 0; c < 4; ++c) kf[c] = *(const short8v*)(kptr + c * 32);
  kptr += 4096;

  for (int kt = 0; kt < 33; ++kt) {
    short8v vf00 = *(const short8v*)(vptr);
    short8v vf01 = *(const short8v*)(vptr + 32);
    short8v vf10 = *(const short8v*)(vptr + 2048);
    short8v vf11 = *(const short8v*)(vptr + 2080);
    vptr += 4096;
    if (kt < 32) {
#pragma unroll
      for (int c = 0; c < 4; ++c) kfn[c] = *(const short8v*)(kptr + c * 32);
      kptr += 4096;
    }
    // S^T[kv][q]: A=K (m=kv=lane&31), B=Q (n=q=lane&31)
    f32x16 s = {};
#pragma unroll
    for (int c = 0; c < 4; ++c)
      s = __builtin_amdgcn_mfma_f32_32x32x16_bf16(kf[c], qf[c], s, 0, 0, 0);

    const float bh_k = bh_lds[row][kt];
    f32x4 ct4[4];
#pragma unroll
    for (int g = 0; g < 4; ++g)
      ct4[g] = *(const f32x4*)&ct_lds[kt * 32 + g * 8 + h * 4];
    float lg[16];
#pragma unroll
    for (int r = 0; r < 16; ++r) {
      const float bh_e = (r == 0) ? ((h == 0) ? bh_prev : bh_k) : bh_k;
      const float ctv = ct4[r >> 2][r & 3];
      const float ec = mzero ? fminf(ctv, MCOL) : ctv;
      lg[r] = fmaf(SCL, s[r], (bh_e + bwv[r]) + ec);
    }
    bh_prev = bh_k;

    float tm = lg[0];
#pragma unroll
    for (int r = 1; r < 16; ++r) tm = fmaxf(tm, lg[r]);
    tm = fmaxf(tm, __shfl_xor(tm, 32));
    if (__any(tm > m_lm + THR_L)) {
      const float nm = fmaxf(m_lm, tm);
      const float rf = fexp2(m_lm - nm);
      m_lm = nm;
      l_lane *= rf;
#pragma unroll
      for (int r = 0; r < 16; ++r) { oaccA[r] *= rf; oaccB[r] *= rf; }
    }
    float p[16], ps = 0.f;
#pragma unroll
    for (int r = 0; r < 16; ++r) { p[r] = fexp2(lg[r] - m_lm); ps += p[r]; }
    l_lane += ps;

    // P (C layout) -> PV B fragments via cvtpk + permlane32_swap
    unsigned int x0 = cvtpk(p[0], p[1]),  x1 = cvtpk(p[2], p[3]);
    unsigned int z0 = cvtpk(p[4], p[5]),  z1 = cvtpk(p[6], p[7]);
    plswap(x0, z0); plswap(x1, z1);
    unsigned int y0 = cvtpk(p[8], p[9]),  y1 = cvtpk(p[10], p[11]);
    unsigned int w0 = cvtpk(p[12], p[13]), w1 = cvtpk(p[14], p[15]);
    plswap(y0, w0); plswap(y1, w1);
    union { unsigned int u[4]; short8v v; } uf;
    uf.u[0] = x0; uf.u[1] = x1; uf.u[2] = z0; uf.u[3] = z1;
    const short8v f1 = uf.v;
    uf.u[0] = y0; uf.u[1] = y1; uf.u[2] = w0; uf.u[3] = w1;
    const short8v f2 = uf.v;

    // O^T[d][q] += V^T-frag x P-frag
    oaccA = __builtin_amdgcn_mfma_f32_32x32x16_bf16(vf00, f1, oaccA, 0, 0, 0);
    oaccA = __builtin_amdgcn_mfma_f32_32x32x16_bf16(vf01, f2, oaccA, 0, 0, 0);
    oaccB = __builtin_amdgcn_mfma_f32_32x32x16_bf16(vf10, f1, oaccB, 0, 0, 0);
    oaccB = __builtin_amdgcn_mfma_f32_32x32x16_bf16(vf11, f2, oaccB, 0, 0, 0);
#pragma unroll
    for (int c = 0; c < 4; ++c) kf[c] = kfn[c];
  }

  // ---- epilogue: combine halves of l, normalize, transpose via T16 ----
  const float l_tot = l_lane + __shfl_xor(l_lane, 32);
  const float inv = 1.f / l_tot;
#pragma unroll
  for (int r = 0; r < 16; r += 2) {
    const int d = (r & 3) + 8 * (r >> 2) + 4 * h;
    *(unsigned int*)&T16[row][d]      = cvtpk(oaccA[r] * inv, oaccA[r + 1] * inv);
    *(unsigned int*)&T16[row][d + 32] = cvtpk(oaccB[r] * inv, oaccB[r + 1] * inv);
  }
  const int q2 = lane >> 1, hb = lane & 1;
  unsigned short* dst =
      ao + (size_t)(b * NSP + qw0 + q2) * DIM + head * HD + hb * 32;
  const unsigned short* srcl = &T16[w * 32 + q2][hb * 32];
#pragma unroll
  for (int i = 0; i < 4; ++i)
    *(short8v*)(dst + i * 8) = *(const short8v*)(srcl + i * 8);
}

// ---------------- final pooling reduce ----------------
__global__ __launch_bounds__(256) void pool_stage2(
    const float* __restrict__ psum, const float* __restrict__ pmax,
    const float* __restrict__ pcnt, float* __restrict__ out)
{
  const int b = blockIdx.y;
  const int c = blockIdx.x * 256 + threadIdx.x;
  float s = 0.f, mx = -3.402823466e+38f;
#pragma unroll
  for (int z = 0; z < 8; ++z) {
    s  += psum[(size_t)(b * 8 + z) * 768 + c];
    mx  = fmaxf(mx, pmax[(size_t)(b * 8 + z) * 768 + c]);
  }
  const float cnt = pcnt[b];
  out[b * 1536 + c]       = s / (cnt + 1e-7f);
  out[b * 1536 + 768 + c] = mx;
}

// ---------------- launch ----------------
extern "C" void kernel_launch(void* const* d_in, const int* in_sizes, int n_in,
                              void* d_out, int out_size, void* d_ws, size_t ws_size,
                              hipStream_t stream) {
  const float* x      = (const float*)d_in[0];
  const unsigned char* mraw = (const unsigned char*)d_in[1];
  const float* qkv_w  = (const float*)d_in[2];
  const float* qkv_b  = (const float*)d_in[3];
  const float* proj_w = (const float*)d_in[4];
  const float* proj_b = (const float*)d_in[5];
  const float* rph    = (const float*)d_in[6];
  const float* rpw    = (const float*)d_in[7];

  char* ws = (char*)d_ws;
  float*          mask_f = (float*)(ws + OFF_MASK);
  float*          pcnt   = (float*)(ws + OFF_PC);
  unsigned short* qkvwT  = (unsigned short*)(ws + OFF_QKVWT);
  unsigned short* projwT = (unsigned short*)(ws + OFF_PROJWT);
  unsigned short* qW     = (unsigned short*)(ws + OFF_Q);
  unsigned short* kW     = (unsigned short*)(ws + OFF_K);
  unsigned short* vW     = (unsigned short*)(ws + OFF_V);
  unsigned short* aoW    = (unsigned short*)(ws + OFF_AO);
  float*          psum   = (float*)(ws + OFF_PS);
  float*          pmax   = (float*)(ws + OFF_PM);
  unsigned short* xb     = (unsigned short*)(ws + OFF_XB);

  prep<<<97, 256, 0, stream>>>(mraw, mask_f, pcnt, kW, vW);
  transpose_cvt2<<<dim3(96, 24), dim3(32, 32), 0, stream>>>(
      qkv_w, proj_w, qkvwT, projwT);
  cvt_f32_bf16<<<2048, 256, 0, stream>>>(x, xb, 8200 * 768 / 4);

  gemm_bf16<0><<<dim3(K3 / 128, 65), 256, 0, stream>>>(
      xb, qkvwT, qkv_b, qW, kW, vW, nullptr, nullptr, nullptr, 8200);

  attn_mfma<<<768, 256, 0, stream>>>(qW, kW, vW, mask_f, rph, rpw, aoW);

  gemm_bf16<1><<<dim3(768 / 128, 64), 256, 0, stream>>>(
      aoW, projwT, proj_b, nullptr, nullptr, nullptr,
      mask_f, psum, pmax, 8192);

  pool_stage2<<<dim3(3, B_), 256, 0, stream>>>(psum, pmax, pcnt, (float*)d_out);
}